// Round 19
// baseline (1447.280 us; speedup 1.0000x reference)
//
#include <hip/hip_runtime.h>
#include <hip/hip_bf16.h>
#include <math.h>

#define NPTS 4096
#define NB 4
#define KNN 20
#define NCOLS (3*NPTS)   // 12288
#define NEG_INF (-__builtin_huge_valf())
#define DNEG_INF (-__builtin_huge_val())

typedef _Float16 f16x8 __attribute__((ext_vector_type(8)));
typedef _Float16 f16x4 __attribute__((ext_vector_type(4)));
typedef float f32x4 __attribute__((ext_vector_type(4)));

// weight-split buffer geometry (elements)
#define WOFF_FC 0
#define WOFF_A0 16384
#define WOFF_F0 344064
#define WOFF_A1 507904
#define WOFF_F1 589824
#define WOFF_SC 671744
#define WOFF_PW 835584
#define WTOT    917504

// ---------------------------------------------------------------------------
// kNN in FP64 — 2 waves per row, 2-level selection (bit-identical ordering).
// ---------------------------------------------------------------------------
__global__ __launch_bounds__(512) void knn_kernel(const float* __restrict__ pc,
                                                  int* __restrict__ idx) {
  __shared__ float pts[NPTS*3];
  __shared__ double msv[2][8];
  __shared__ int    msn[2][8];
  int b = blockIdx.x >> 10;           // 1024 blocks per batch
  int rowblk = blockIdx.x & 1023;
  const float* pb = pc + (size_t)b*NPTS*3;
  for (int i = threadIdx.x; i < NPTS*3; i += 512) pts[i] = pb[i];
  __syncthreads();
  int wave = threadIdx.x >> 6;        // 0..7
  int lane = threadIdx.x & 63;
  int row  = wave >> 1;               // 0..3
  int half = wave & 1;
  int l128 = half*64 + lane;          // 0..127
  int n = rowblk*4 + row;
  double pn0 = pts[n*3+0], pn1 = pts[n*3+1], pn2 = pts[n*3+2];
  double sqn = pn0*pn0 + pn1*pn1 + pn2*pn2;
  double nd[32];
#pragma unroll
  for (int j = 0; j < 32; ++j) {
    int m = j*128 + l128;
    double q0 = pts[m*3+0], q1 = pts[m*3+1], q2 = pts[m*3+2];
    double inner = pn0*q0 + pn1*q1 + pn2*q2;
    double sqm = q0*q0 + q1*q1 + q2*q2;
    nd[j] = 2.0*inner - sqn - sqm;
  }
  double gm[2]; int gj[2];
#pragma unroll
  for (int g = 0; g < 2; ++g) {
    double v = nd[g*16]; int jb = g*16;
#pragma unroll
    for (int jj = 1; jj < 16; ++jj) {
      int j = g*16 + jj;
      bool take = nd[j] > v;
      v = take ? nd[j] : v;
      jb = take ? j : jb;
    }
    gm[g] = v; gj[g] = jb;
  }
  int* orow = idx + ((size_t)b*NPTS + n)*KNN;
  for (int t = 0; t < KNN; ++t) {
    double bv = gm[0]; int bj = gj[0];
    if (gm[1] > bv) { bv = gm[1]; bj = gj[1]; }
    int bm = bj*128 + l128;
#pragma unroll
    for (int s = 1; s < 64; s <<= 1) {
      double ov = __shfl_xor(bv, s, 64);
      int om = __shfl_xor(bm, s, 64);
      bool take = (ov > bv) || (ov == bv && om < bm);
      bv = take ? ov : bv;
      bm = take ? om : bm;
    }
    if (lane == 0) { msv[t&1][wave] = bv; msn[t&1][wave] = bm; }
    __syncthreads();
    {
      double pv = msv[t&1][wave^1]; int pm = msn[t&1][wave^1];
      bool take = (pv > bv) || (pv == bv && pm < bm);
      bv = take ? pv : bv;
      bm = take ? pm : bm;
    }
    if (half == 0 && lane == 0) orow[t] = bm;
    if (t < KNN-1) {
      int vic_l128 = bm & 127;
      int jw = bm >> 7;
      int vic_half = vic_l128 >> 6;
      if (vic_half == half) {           // wave-uniform: only victim's wave pays
        bool iswl = (l128 == vic_l128);
        int gw = jw >> 4;
#define REBUILD(G) { \
  _Pragma("unroll") \
  for (int jj = 0; jj < 16; ++jj) { \
    int j = (G)*16 + jj; \
    if (iswl && j == jw) nd[j] = DNEG_INF; \
  } \
  double v = nd[(G)*16]; int jb = (G)*16; \
  _Pragma("unroll") \
  for (int jj = 1; jj < 16; ++jj) { \
    int j = (G)*16 + jj; \
    bool take = nd[j] > v; \
    v = take ? nd[j] : v; \
    jb = take ? j : jb; \
  } \
  gm[G] = v; gj[G] = jb; \
}
        if (gw == 0) REBUILD(0)
        else         REBUILD(1)
#undef REBUILD
      }
    }
  }
}

// ---------------------------------------------------------------------------
// Edge conv v3b — identical arithmetic to v3; Wp high half (j>=32) is read
// from a transposed LDS copy (stride-1 per lane, conflict-free) instead of
// registers, cutting wrow from 64 -> 32 VGPRs (occupancy 4 -> 5 waves/SIMD).
// fp32 compute, fp64 final dot+compare. 2 waves per 128-thread block.
// Output conv[b][v*N+n][c], c<64.
// ---------------------------------------------------------------------------
#define ECH 5
__global__ __launch_bounds__(128) void edgeconv_kernel(
    const float* __restrict__ pc, const int* __restrict__ knnidx,
    const float* __restrict__ Wf, const float* __restrict__ Wd,
    const float* __restrict__ Wp, float* __restrict__ outp) {
  __shared__ float xls[2*ECH*3*64];   // per wave: x[(v*ECH+kc)*64 + c]
  __shared__ float wpT[32*64];        // wpT[j-32][c] = Wp[c][j], j in [32,64)
  int wave = threadIdx.x >> 6, lane = threadIdx.x & 63;
  int pid0 = blockIdx.x * 2;
  int b = pid0 >> 12;
  int n = (pid0 & (NPTS-1)) + wave;
  const float* pb = pc + (size_t)b*NPTS*3;
  int c = lane;
  for (int idx = threadIdx.x; idx < 32*64; idx += 128) {
    int jj = idx >> 6, cc = idx & 63;
    wpT[jj*64 + cc] = Wp[cc*64 + 32 + jj];
  }
  float wrow[32];
#pragma unroll
  for (int j = 0; j < 32; ++j) wrow[j] = Wp[c*64 + j];
  float wf0 = Wf[c*3+0], wf1 = Wf[c*3+1], wf2 = Wf[c*3+2];
  float wd0 = Wd[c*3+0], wd1 = Wd[c*3+1], wd2 = Wd[c*3+2];
  float f9[9];
#pragma unroll
  for (int i = 0; i < 9; ++i) f9[i] = 0.0f;
  if (lane < KNN) {
    int j = knnidx[((size_t)b*NPTS + n)*KNN + lane];
    float q0 = pb[j*3+0], q1 = pb[j*3+1], q2 = pb[j*3+2];
    float x0 = pb[n*3+0], x1 = pb[n*3+1], x2 = pb[n*3+2];
    f9[0] = q0-x0; f9[1] = q1-x1; f9[2] = q2-x2;
    f9[3] = x0;    f9[4] = x1;    f9[5] = x2;
    f9[6] = q1*x2 - q2*x1;
    f9[7] = q2*x0 - q0*x2;
    f9[8] = q0*x1 - q1*x0;
  }
  __syncthreads();                    // wpT ready
  float* xw = &xls[wave*ECH*3*64];
  double bdot = DNEG_INF;
  float bx0 = 0.f, bx1 = 0.f, bx2 = 0.f;
  for (int k0 = 0; k0 < KNN; k0 += ECH) {
    for (int kc = 0; kc < ECH; ++kc) {
      int kk = k0 + kc;
      float fch[9];
#pragma unroll
      for (int i = 0; i < 9; ++i) fch[i] = __shfl(f9[i], kk, 64);
      float fv[3], dv[3];
#pragma unroll
      for (int v = 0; v < 3; ++v) {
        fv[v] = wf0*fch[v] + wf1*fch[3+v] + wf2*fch[6+v];
        dv[v] = wd0*fch[v] + wd1*fch[3+v] + wd2*fch[6+v];
      }
      float dot = fv[0]*dv[0] + fv[1]*dv[1] + fv[2]*dv[2];
      if (dot < 0.0f) {
        float dsq = dv[0]*dv[0] + dv[1]*dv[1] + dv[2]*dv[2];
        float s = dot / (dsq + 1e-6f);
        fv[0] -= s*dv[0]; fv[1] -= s*dv[1]; fv[2] -= s*dv[2];
      }
      xw[(0*ECH+kc)*64 + c] = fv[0];
      xw[(1*ECH+kc)*64 + c] = fv[1];
      xw[(2*ECH+kc)*64 + c] = fv[2];
    }
    for (int kc = 0; kc < ECH; ++kc) {
      float a0 = 0.f, a1 = 0.f, a2 = 0.f;
#pragma unroll
      for (int j = 0; j < 32; j += 4) {
        float4 v0 = *(const float4*)&xw[(0*ECH+kc)*64 + j];
        float4 v1 = *(const float4*)&xw[(1*ECH+kc)*64 + j];
        float4 v2 = *(const float4*)&xw[(2*ECH+kc)*64 + j];
        a0 += wrow[j]*v0.x + wrow[j+1]*v0.y + wrow[j+2]*v0.z + wrow[j+3]*v0.w;
        a1 += wrow[j]*v1.x + wrow[j+1]*v1.y + wrow[j+2]*v1.z + wrow[j+3]*v1.w;
        a2 += wrow[j]*v2.x + wrow[j+1]*v2.y + wrow[j+2]*v2.z + wrow[j+3]*v2.w;
      }
#pragma unroll
      for (int j = 32; j < 64; j += 4) {
        float4 v0 = *(const float4*)&xw[(0*ECH+kc)*64 + j];
        float4 v1 = *(const float4*)&xw[(1*ECH+kc)*64 + j];
        float4 v2 = *(const float4*)&xw[(2*ECH+kc)*64 + j];
        float w0 = wpT[(j-32)*64 + c];
        float w1 = wpT[(j-31)*64 + c];
        float w2 = wpT[(j-30)*64 + c];
        float w3 = wpT[(j-29)*64 + c];
        a0 += w0*v0.x + w1*v0.y + w2*v0.z + w3*v0.w;
        a1 += w0*v1.x + w1*v1.y + w2*v1.z + w3*v1.w;
        a2 += w0*v2.x + w1*v2.y + w2*v2.z + w3*v2.w;
      }
      float xc0 = xw[(0*ECH+kc)*64 + c];
      float xc1 = xw[(1*ECH+kc)*64 + c];
      float xc2 = xw[(2*ECH+kc)*64 + c];
      double dd = (double)xc0*a0 + (double)xc1*a1 + (double)xc2*a2;
      bool take = dd > bdot;          // kk ascending + strict > = first max
      bdot = take ? dd : bdot;
      bx0 = take ? xc0 : bx0;
      bx1 = take ? xc1 : bx1;
      bx2 = take ? xc2 : bx2;
    }
  }
  outp[((size_t)b*NCOLS + 0*NPTS + n)*64 + c] = bx0;
  outp[((size_t)b*NCOLS + 1*NPTS + n)*64 + c] = bx1;
  outp[((size_t)b*NCOLS + 2*NPTS + n)*64 + c] = bx2;
}

// ---------------------------------------------------------------------------
// one-shot weight split: fp32 -> f16 hi (at [i]) + f16 lo (at [i+WTOT])
// ---------------------------------------------------------------------------
__global__ __launch_bounds__(256) void wsplit_kernel(
    const float* __restrict__ fc, const float* __restrict__ a0,
    const float* __restrict__ f0, const float* __restrict__ a1,
    const float* __restrict__ f1, const float* __restrict__ sc,
    const float* __restrict__ pw, _Float16* __restrict__ outp) {
  int i = blockIdx.x*256 + threadIdx.x;
  const float* src; int off;
  if      (i < WOFF_A0) { src = fc; off = WOFF_FC; }
  else if (i < WOFF_F0) { src = a0; off = WOFF_A0; }
  else if (i < WOFF_A1) { src = f0; off = WOFF_F0; }
  else if (i < WOFF_F1) { src = a1; off = WOFF_A1; }
  else if (i < WOFF_SC) { src = f1; off = WOFF_F1; }
  else if (i < WOFF_PW) { src = sc; off = WOFF_SC; }
  else                  { src = pw; off = WOFF_PW; }
  float w = src[i - off];
  _Float16 h = (_Float16)w;
  outp[i] = h;
  outp[i + WTOT] = (_Float16)(w - (float)h);
}

// ---------------------------------------------------------------------------
// MFMA GEMM — BM=64 x BN=128 tile. fp16x2 split, pre-split W.
// ---------------------------------------------------------------------------
#define LDP 40
__global__ __launch_bounds__(256) void gemm_mfma(
    const _Float16* __restrict__ Wh, const _Float16* __restrict__ Wl,
    const float* __restrict__ X, const float* __restrict__ Z,
    const float* __restrict__ bias, float* __restrict__ Y,
    int Cin, int Wstride, int ldX, int ldY, int ldZ, int addZ, int Cbias) {
  __shared__ __align__(16) _Float16 Ah[64*LDP];
  __shared__ __align__(16) _Float16 Al[64*LDP];
  __shared__ __align__(16) _Float16 Bh[128*LDP];
  __shared__ __align__(16) _Float16 Bl[128*LDP];
  int b = blockIdx.z;
  int sp0 = blockIdx.x * 64;
  int co0 = blockIdx.y * 128;
  const float* Xb = X + ((size_t)b*NCOLS + sp0) * ldX;
  int t = threadIdx.x;
  int arow = t >> 2, akoff = (t & 3) * 8;
  int brow = t >> 1, bkoff = (t & 1) * 16;
  int wid = t >> 6, lane = t & 63;
  int wr = (wid >> 1) * 32, wc = (wid & 1) * 64;
  int lrow = lane & 15, lk = (lane >> 4) * 8;
  f32x4 acc[2][4];
#pragma unroll
  for (int f = 0; f < 2; ++f)
#pragma unroll
    for (int g = 0; g < 4; ++g)
#pragma unroll
      for (int r = 0; r < 4; ++r) acc[f][g][r] = 0.0f;

  for (int k0 = 0; k0 < Cin; k0 += 32) {
    const float* xs = Xb + (size_t)arow*ldX + k0 + akoff;
    float xv[8];
    *(float4*)&xv[0] = *(const float4*)&xs[0];
    *(float4*)&xv[4] = *(const float4*)&xs[4];
    _Float16 xh[8], xl[8];
#pragma unroll
    for (int j = 0; j < 8; ++j) {
      _Float16 h = (_Float16)xv[j];
      xh[j] = h; xl[j] = (_Float16)(xv[j] - (float)h);
    }
    *(f16x8*)&Ah[arow*LDP + akoff] = *(f16x8*)&xh[0];
    *(f16x8*)&Al[arow*LDP + akoff] = *(f16x8*)&xl[0];
    const _Float16* whs = Wh + (size_t)(co0 + brow)*Wstride + k0 + bkoff;
    const _Float16* wls = Wl + (size_t)(co0 + brow)*Wstride + k0 + bkoff;
    *(f16x8*)&Bh[brow*LDP + bkoff]     = *(const f16x8*)&whs[0];
    *(f16x8*)&Bh[brow*LDP + bkoff + 8] = *(const f16x8*)&whs[8];
    *(f16x8*)&Bl[brow*LDP + bkoff]     = *(const f16x8*)&wls[0];
    *(f16x8*)&Bl[brow*LDP + bkoff + 8] = *(const f16x8*)&wls[8];
    __syncthreads();
    f16x8 ah[2], al[2], bh[4], bl[4];
#pragma unroll
    for (int f = 0; f < 2; ++f) {
      ah[f] = *(f16x8*)&Ah[(wr + f*16 + lrow)*LDP + lk];
      al[f] = *(f16x8*)&Al[(wr + f*16 + lrow)*LDP + lk];
    }
#pragma unroll
    for (int g = 0; g < 4; ++g) {
      bh[g] = *(f16x8*)&Bh[(wc + g*16 + lrow)*LDP + lk];
      bl[g] = *(f16x8*)&Bl[(wc + g*16 + lrow)*LDP + lk];
    }
#pragma unroll
    for (int f = 0; f < 2; ++f)
#pragma unroll
      for (int g = 0; g < 4; ++g) {
        acc[f][g] = __builtin_amdgcn_mfma_f32_16x16x32_f16(ah[f], bh[g], acc[f][g], 0, 0, 0);
        acc[f][g] = __builtin_amdgcn_mfma_f32_16x16x32_f16(ah[f], bl[g], acc[f][g], 0, 0, 0);
        acc[f][g] = __builtin_amdgcn_mfma_f32_16x16x32_f16(al[f], bh[g], acc[f][g], 0, 0, 0);
      }
    __syncthreads();
  }
  int lr0 = (lane >> 4) * 4, lc = lane & 15;
  float badd[4] = {0.f, 0.f, 0.f, 0.f};
  if (bias) {
    int v = sp0 >> 12;
    const float* brow2 = bias + ((size_t)b*3 + v)*Cbias;
#pragma unroll
    for (int g = 0; g < 4; ++g) badd[g] = brow2[co0 + wc + g*16 + lc];
  }
#pragma unroll
  for (int f = 0; f < 2; ++f)
#pragma unroll
    for (int g = 0; g < 4; ++g)
#pragma unroll
      for (int r = 0; r < 4; ++r) {
        int sp = sp0 + wr + f*16 + lr0 + r;
        int co = co0 + wc + g*16 + lc;
        float val = acc[f][g][r] + badd[g];
        if (addZ) val += Z[((size_t)b*NCOLS + sp)*ldZ + co];
        Y[((size_t)b*NCOLS + sp)*ldY + co] = val;
      }
}

// ---------------------------------------------------------------------------
// DUAL GEMM: Y = W1 @ X1 + W2 @ X2 (+bias).
// ---------------------------------------------------------------------------
__global__ __launch_bounds__(256) void gemm_dual(
    const _Float16* __restrict__ W1h, const _Float16* __restrict__ W1l,
    const _Float16* __restrict__ W2h, const _Float16* __restrict__ W2l,
    const float* __restrict__ X1, const float* __restrict__ X2s,
    const float* __restrict__ bias, float* __restrict__ Y,
    int K2, int ldY, int Cbias) {
  __shared__ __align__(16) _Float16 Ah[64*LDP];
  __shared__ __align__(16) _Float16 Al[64*LDP];
  __shared__ __align__(16) _Float16 Bh[128*LDP];
  __shared__ __align__(16) _Float16 Bl[128*LDP];
  int b = blockIdx.z;
  int sp0 = blockIdx.x * 64;
  int co0 = blockIdx.y * 128;
  int t = threadIdx.x;
  int arow = t >> 2, akoff = (t & 3) * 8;
  int brow = t >> 1, bkoff = (t & 1) * 16;
  int wid = t >> 6, lane = t & 63;
  int wr = (wid >> 1) * 32, wc = (wid & 1) * 64;
  int lrow = lane & 15, lk = (lane >> 4) * 8;
  f32x4 acc[2][4];
#pragma unroll
  for (int f = 0; f < 2; ++f)
#pragma unroll
    for (int g = 0; g < 4; ++g)
#pragma unroll
      for (int r = 0; r < 4; ++r) acc[f][g][r] = 0.0f;

  int Ktot = 128 + K2;
  for (int k0 = 0; k0 < Ktot; k0 += 32) {
    const float* xs;
    const _Float16 *whs, *wls;
    if (k0 < 128) {
      xs  = X1 + ((size_t)b*NCOLS + sp0 + arow)*128 + k0 + akoff;
      whs = W1h + (size_t)(co0 + brow)*128 + k0 + bkoff;
      wls = W1l + (size_t)(co0 + brow)*128 + k0 + bkoff;
    } else {
      xs  = X2s + ((size_t)b*NCOLS + sp0 + arow)*256 + (k0-128) + akoff;
      whs = W2h + (size_t)(co0 + brow)*256 + (k0-128) + bkoff;
      wls = W2l + (size_t)(co0 + brow)*256 + (k0-128) + bkoff;
    }
    float xv[8];
    *(float4*)&xv[0] = *(const float4*)&xs[0];
    *(float4*)&xv[4] = *(const float4*)&xs[4];
    _Float16 xh[8], xl[8];
#pragma unroll
    for (int j = 0; j < 8; ++j) {
      _Float16 h = (_Float16)xv[j];
      xh[j] = h; xl[j] = (_Float16)(xv[j] - (float)h);
    }
    *(f16x8*)&Ah[arow*LDP + akoff] = *(f16x8*)&xh[0];
    *(f16x8*)&Al[arow*LDP + akoff] = *(f16x8*)&xl[0];
    *(f16x8*)&Bh[brow*LDP + bkoff]     = *(const f16x8*)&whs[0];
    *(f16x8*)&Bh[brow*LDP + bkoff + 8] = *(const f16x8*)&whs[8];
    *(f16x8*)&Bl[brow*LDP + bkoff]     = *(const f16x8*)&wls[0];
    *(f16x8*)&Bl[brow*LDP + bkoff + 8] = *(const f16x8*)&wls[8];
    __syncthreads();
    f16x8 ah[2], al[2], bh[4], bl[4];
#pragma unroll
    for (int f = 0; f < 2; ++f) {
      ah[f] = *(f16x8*)&Ah[(wr + f*16 + lrow)*LDP + lk];
      al[f] = *(f16x8*)&Al[(wr + f*16 + lrow)*LDP + lk];
    }
#pragma unroll
    for (int g = 0; g < 4; ++g) {
      bh[g] = *(f16x8*)&Bh[(wc + g*16 + lrow)*LDP + lk];
      bl[g] = *(f16x8*)&Bl[(wc + g*16 + lrow)*LDP + lk];
    }
#pragma unroll
    for (int f = 0; f < 2; ++f)
#pragma unroll
      for (int g = 0; g < 4; ++g) {
        acc[f][g] = __builtin_amdgcn_mfma_f32_16x16x32_f16(ah[f], bh[g], acc[f][g], 0, 0, 0);
        acc[f][g] = __builtin_amdgcn_mfma_f32_16x16x32_f16(ah[f], bl[g], acc[f][g], 0, 0, 0);
        acc[f][g] = __builtin_amdgcn_mfma_f32_16x16x32_f16(al[f], bh[g], acc[f][g], 0, 0, 0);
      }
    __syncthreads();
  }
  int lr0 = (lane >> 4) * 4, lc = lane & 15;
  float badd[4] = {0.f, 0.f, 0.f, 0.f};
  if (bias) {
    int v = sp0 >> 12;
    const float* brow2 = bias + ((size_t)b*3 + v)*Cbias;
#pragma unroll
    for (int g = 0; g < 4; ++g) badd[g] = brow2[co0 + wc + g*16 + lc];
  }
#pragma unroll
  for (int f = 0; f < 2; ++f)
#pragma unroll
    for (int g = 0; g < 4; ++g)
#pragma unroll
      for (int r = 0; r < 4; ++r) {
        int sp = sp0 + wr + f*16 + lr0 + r;
        int co = co0 + wc + g*16 + lc;
        Y[((size_t)b*NCOLS + sp)*ldY + co] = acc[f][g][r] + badd[g];
      }
}

// ---------------------------------------------------------------------------
// FUSED GEMM + vn_leaky.
// ---------------------------------------------------------------------------
template<int FM>
__global__ __launch_bounds__(256) void gemm_leaky(
    const _Float16* __restrict__ Wh, const _Float16* __restrict__ Wl,
    const float* __restrict__ X, const float* __restrict__ pooled,
    const float* __restrict__ bias, float* __restrict__ Y,
    int Cin, int Wstride, int ldX, int ldY, int Cbias) {
  constexpr int BM = FM*32;
  __shared__ __align__(16) _Float16 Ah[BM*LDP];
  __shared__ __align__(16) _Float16 Al[BM*LDP];
  __shared__ __align__(16) _Float16 Bh[128*LDP];
  __shared__ __align__(16) _Float16 Bl[128*LDP];
  int b = blockIdx.z;
  int n0 = blockIdx.x * BM;
  int co0 = blockIdx.y * 128;
  int t = threadIdx.x;
  constexpr int APT = BM/8;
  constexpr int TPR = 32/APT;
  int arow = t / TPR, akoff = (t % TPR) * APT;
  int brow = t >> 1, bkoff = (t & 1) * 16;
  int wid = t >> 6, lane = t & 63;
  int wr = (wid >> 1) * (BM/2), wc = (wid & 1) * 64;
  int lrow = lane & 15, lk = (lane >> 4) * 8;
  f32x4 acc[3][FM][4];
#pragma unroll
  for (int v = 0; v < 3; ++v)
#pragma unroll
    for (int f = 0; f < FM; ++f)
#pragma unroll
      for (int g = 0; g < 4; ++g)
#pragma unroll
        for (int r = 0; r < 4; ++r) acc[v][f][g][r] = 0.0f;

  for (int v = 0; v < 3; ++v) {
    const float* Xb = X + ((size_t)b*NCOLS + (size_t)v*NPTS + n0) * ldX;
    for (int k0 = 0; k0 < Cin; k0 += 32) {
      const float* xs = Xb + (size_t)arow*ldX + k0 + akoff;
      float xv[APT];
#pragma unroll
      for (int j = 0; j < APT; j += 4)
        *(float4*)&xv[j] = *(const float4*)&xs[j];
      _Float16 xh[APT], xl[APT];
#pragma unroll
      for (int j = 0; j < APT; ++j) {
        _Float16 h = (_Float16)xv[j];
        xh[j] = h; xl[j] = (_Float16)(xv[j] - (float)h);
      }
      if (APT == 8) {
        *(f16x8*)&Ah[arow*LDP + akoff] = *(f16x8*)&xh[0];
        *(f16x8*)&Al[arow*LDP + akoff] = *(f16x8*)&xl[0];
      } else {
        *(f16x4*)&Ah[arow*LDP + akoff] = *(f16x4*)&xh[0];
        *(f16x4*)&Al[arow*LDP + akoff] = *(f16x4*)&xl[0];
      }
      const _Float16* whs = Wh + (size_t)(co0 + brow)*Wstride + k0 + bkoff;
      const _Float16* wls = Wl + (size_t)(co0 + brow)*Wstride + k0 + bkoff;
      *(f16x8*)&Bh[brow*LDP + bkoff]     = *(const f16x8*)&whs[0];
      *(f16x8*)&Bh[brow*LDP + bkoff + 8] = *(const f16x8*)&whs[8];
      *(f16x8*)&Bl[brow*LDP + bkoff]     = *(const f16x8*)&wls[0];
      *(f16x8*)&Bl[brow*LDP + bkoff + 8] = *(const f16x8*)&wls[8];
      __syncthreads();
      f16x8 ah[FM], al[FM], bh[4], bl[4];
#pragma unroll
      for (int f = 0; f < FM; ++f) {
        ah[f] = *(f16x8*)&Ah[(wr + f*16 + lrow)*LDP + lk];
        al[f] = *(f16x8*)&Al[(wr + f*16 + lrow)*LDP + lk];
      }
#pragma unroll
      for (int g = 0; g < 4; ++g) {
        bh[g] = *(f16x8*)&Bh[(wc + g*16 + lrow)*LDP + lk];
        bl[g] = *(f16x8*)&Bl[(wc + g*16 + lrow)*LDP + lk];
      }
#pragma unroll
      for (int f = 0; f < FM; ++f)
#pragma unroll
        for (int g = 0; g < 4; ++g) {
          acc[v][f][g] = __builtin_amdgcn_mfma_f32_16x16x32_f16(ah[f], bh[g], acc[v][f][g], 0, 0, 0);
          acc[v][f][g] = __builtin_amdgcn_mfma_f32_16x16x32_f16(ah[f], bl[g], acc[v][f][g], 0, 0, 0);
          acc[v][f][g] = __builtin_amdgcn_mfma_f32_16x16x32_f16(al[f], bh[g], acc[v][f][g], 0, 0, 0);
        }
      __syncthreads();
    }
  }
  int lr0 = (lane >> 4) * 4, lc = lane & 15;
  float badd[3][4];
#pragma unroll
  for (int v = 0; v < 3; ++v)
#pragma unroll
    for (int g = 0; g < 4; ++g) {
      badd[v][g] = bias ? bias[((size_t)b*3 + v)*Cbias + co0 + wc + g*16 + lc] : 0.0f;
    }
  bool xfromX = (pooled == nullptr) || (co0 < 128);
#pragma unroll
  for (int f = 0; f < FM; ++f)
#pragma unroll
    for (int g = 0; g < 4; ++g)
#pragma unroll
      for (int r = 0; r < 4; ++r) {
        int n = n0 + wr + f*16 + lr0 + r;
        int co = co0 + wc + g*16 + lc;
        float x0, x1, x2;
        if (xfromX) {
          x0 = X[((size_t)b*NCOLS + 0*NPTS + n)*ldX + co];
          x1 = X[((size_t)b*NCOLS + 1*NPTS + n)*ldX + co];
          x2 = X[((size_t)b*NCOLS + 2*NPTS + n)*ldX + co];
        } else {
          const float* pp = pooled + (size_t)b*384 + (co - 128)*3;
          x0 = pp[0]; x1 = pp[1]; x2 = pp[2];
        }
        float d0 = acc[0][f][g][r] + badd[0][g];
        float d1 = acc[1][f][g][r] + badd[1][g];
        float d2 = acc[2][f][g][r] + badd[2][g];
        float dot = x0*d0 + x1*d1 + x2*d2;
        float u0 = x0, u1 = x1, u2 = x2;
        if (dot < 0.0f) {
          float dsq = d0*d0 + d1*d1 + d2*d2;
          float s = dot / (dsq + 1e-6f);
          u0 = x0 - s*d0; u1 = x1 - s*d1; u2 = x2 - s*d2;
        }
        Y[((size_t)b*NCOLS + 0*NPTS + n)*ldY + co] = u0;
        Y[((size_t)b*NCOLS + 1*NPTS + n)*ldY + co] = u1;
        Y[((size_t)b*NCOLS + 2*NPTS + n)*ldY + co] = u2;
      }
}

// ---------------------------------------------------------------------------
// FUSED pw-GEMM + pool-over-N partial argmax.
// ---------------------------------------------------------------------------
__global__ __launch_bounds__(256) void gemm_pool(
    const _Float16* __restrict__ Wh, const _Float16* __restrict__ Wl,
    const float* __restrict__ X,
    double* __restrict__ pv, int* __restrict__ pn) {
  __shared__ __align__(16) _Float16 Ah[64*LDP];
  __shared__ __align__(16) _Float16 Al[64*LDP];
  __shared__ __align__(16) _Float16 Bh[128*LDP];
  __shared__ __align__(16) _Float16 Bl[128*LDP];
  int b = blockIdx.z;
  int n0 = blockIdx.x * 64;
  int t = threadIdx.x;
  int arow = t >> 2, akoff = (t & 3) * 8;
  int brow = t >> 1, bkoff = (t & 1) * 16;
  int wid = t >> 6, lane = t & 63;
  int wr = (wid >> 1) * 32, wc = (wid & 1) * 64;
  int lrow = lane & 15, lk = (lane >> 4) * 8;
  f32x4 acc[3][2][4];
#pragma unroll
  for (int v = 0; v < 3; ++v)
#pragma unroll
    for (int f = 0; f < 2; ++f)
#pragma unroll
      for (int g = 0; g < 4; ++g)
#pragma unroll
        for (int r = 0; r < 4; ++r) acc[v][f][g][r] = 0.0f;

  for (int v = 0; v < 3; ++v) {
    const float* Xb = X + ((size_t)b*NCOLS + (size_t)v*NPTS + n0) * 256;
    for (int k0 = 0; k0 < 128; k0 += 32) {
      const float* xs = Xb + (size_t)arow*256 + k0 + akoff;
      float xv[8];
      *(float4*)&xv[0] = *(const float4*)&xs[0];
      *(float4*)&xv[4] = *(const float4*)&xs[4];
      _Float16 xh[8], xl[8];
#pragma unroll
      for (int j = 0; j < 8; ++j) {
        _Float16 h = (_Float16)xv[j];
        xh[j] = h; xl[j] = (_Float16)(xv[j] - (float)h);
      }
      *(f16x8*)&Ah[arow*LDP + akoff] = *(f16x8*)&xh[0];
      *(f16x8*)&Al[arow*LDP + akoff] = *(f16x8*)&xl[0];
      const _Float16* whs = Wh + (size_t)brow*128 + k0 + bkoff;
      const _Float16* wls = Wl + (size_t)brow*128 + k0 + bkoff;
      *(f16x8*)&Bh[brow*LDP + bkoff]     = *(const f16x8*)&whs[0];
      *(f16x8*)&Bh[brow*LDP + bkoff + 8] = *(const f16x8*)&whs[8];
      *(f16x8*)&Bl[brow*LDP + bkoff]     = *(const f16x8*)&wls[0];
      *(f16x8*)&Bl[brow*LDP + bkoff + 8] = *(const f16x8*)&wls[8];
      __syncthreads();
      f16x8 ah[2], al[2], bh[4], bl[4];
#pragma unroll
      for (int f = 0; f < 2; ++f) {
        ah[f] = *(f16x8*)&Ah[(wr + f*16 + lrow)*LDP + lk];
        al[f] = *(f16x8*)&Al[(wr + f*16 + lrow)*LDP + lk];
      }
#pragma unroll
      for (int g = 0; g < 4; ++g) {
        bh[g] = *(f16x8*)&Bh[(wc + g*16 + lrow)*LDP + lk];
        bl[g] = *(f16x8*)&Bl[(wc + g*16 + lrow)*LDP + lk];
      }
#pragma unroll
      for (int f = 0; f < 2; ++f)
#pragma unroll
        for (int g = 0; g < 4; ++g) {
          acc[v][f][g] = __builtin_amdgcn_mfma_f32_16x16x32_f16(ah[f], bh[g], acc[v][f][g], 0, 0, 0);
          acc[v][f][g] = __builtin_amdgcn_mfma_f32_16x16x32_f16(ah[f], bl[g], acc[v][f][g], 0, 0, 0);
          acc[v][f][g] = __builtin_amdgcn_mfma_f32_16x16x32_f16(al[f], bh[g], acc[v][f][g], 0, 0, 0);
        }
      __syncthreads();
    }
  }
  int lr0 = (lane >> 4) * 4, lc = lane & 15;
  double bestv[4]; int bestn[4];
#pragma unroll
  for (int g = 0; g < 4; ++g) { bestv[g] = DNEG_INF; bestn[g] = 0x7fffffff; }
#pragma unroll
  for (int f = 0; f < 2; ++f)
#pragma unroll
    for (int r = 0; r < 4; ++r) {
      int n = n0 + wr + f*16 + lr0 + r;
#pragma unroll
      for (int g = 0; g < 4; ++g) {
        int co = wc + g*16 + lc;
        double dot =
            (double)X[((size_t)b*NCOLS + 0*NPTS + n)*256 + co] * (double)acc[0][f][g][r]
          + (double)X[((size_t)b*NCOLS + 1*NPTS + n)*256 + co] * (double)acc[1][f][g][r]
          + (double)X[((size_t)b*NCOLS + 2*NPTS + n)*256 + co] * (double)acc[2][f][g][r];
        bool take = (dot > bestv[g]) || (dot == bestv[g] && n < bestn[g]);
        bestv[g] = take ? dot : bestv[g];
        bestn[g] = take ? n : bestn[g];
      }
    }
#pragma unroll
  for (int s = 16; s < 64; s <<= 1) {
#pragma unroll
    for (int g = 0; g < 4; ++g) {
      double ov = __shfl_xor(bestv[g], s, 64);
      int on = __shfl_xor(bestn[g], s, 64);
      bool take = (ov > bestv[g]) || (ov == bestv[g] && on < bestn[g]);
      bestv[g] = take ? ov : bestv[g];
      bestn[g] = take ? on : bestn[g];
    }
  }
  double* cdv = (double*)Ah;
  int*    cdn = (int*)Bh;
  if (lane < 16) {
#pragma unroll
    for (int g = 0; g < 4; ++g) {
      cdv[(wid*4 + g)*16 + lane] = bestv[g];
      cdn[(wid*4 + g)*16 + lane] = bestn[g];
    }
  }
  __syncthreads();
  if (t < 128) {
    int c = t;
    int wq = c >> 6;
    int g = (c >> 4) & 3, l2 = c & 15;
    double v0 = cdv[((wq)*4 + g)*16 + l2];   int n0v = cdn[((wq)*4 + g)*16 + l2];
    double v1 = cdv[((wq+2)*4 + g)*16 + l2]; int n1v = cdn[((wq+2)*4 + g)*16 + l2];
    bool take = (v1 > v0) || (v1 == v0 && n1v < n0v);
    double bv = take ? v1 : v0;
    int bn = take ? n1v : n0v;
    pv[((size_t)b*64 + blockIdx.x)*128 + c] = bv;
    pn[((size_t)b*64 + blockIdx.x)*128 + c] = bn;
  }
}

// ---------------------------------------------------------------------------
// FUSED pool stage-2 + next-iteration concat-bias. One block per b, 128 thr.
// Part 1 identical to pool2_kernel; part 2 identical arithmetic to bias2.
// ---------------------------------------------------------------------------
__global__ __launch_bounds__(128) void pool2bias_kernel(
    const double* __restrict__ pv, const int* __restrict__ pn,
    const float* __restrict__ Net, float* __restrict__ pooled,
    const float* __restrict__ Wa0, const float* __restrict__ Wsc,
    float* __restrict__ biasA, float* __restrict__ biasS, int lastIter) {
  __shared__ float pl[384];
  int b = blockIdx.x, c = threadIdx.x;
  double bv = DNEG_INF; int bn = 0x7fffffff;
  for (int ch = 0; ch < 64; ++ch) {
    double v = pv[((size_t)b*64 + ch)*128 + c];
    int nn = pn[((size_t)b*64 + ch)*128 + c];
    if (v > bv || (v == bv && nn < bn)) { bv = v; bn = nn; }
  }
#pragma unroll
  for (int v = 0; v < 3; ++v) {
    float val = Net[((size_t)b*NCOLS + v*NPTS + bn)*256 + c];
    pooled[(size_t)b*384 + c*3 + v] = val;
    pl[c*3 + v] = val;
  }
  if (lastIter) return;
  __syncthreads();
  for (int tt = c; tt < 1152; tt += 128) {    // 3*256 (A) + 3*128 (S)
    const float* wr; float* dst; int v;
    if (tt < 768) {
      v = tt >> 8; int co = tt & 255;
      wr = Wa0 + (size_t)co*256 + 128;
      dst = &biasA[((size_t)b*3 + v)*256 + co];
    } else {
      int u = tt - 768;
      v = u >> 7; int co = u & 127;
      wr = Wsc + (size_t)co*256 + 128;
      dst = &biasS[((size_t)b*3 + v)*128 + co];
    }
    double acc = 0.0;
#pragma unroll 4
    for (int cc = 0; cc < 128; ++cc)
      acc += (double)wr[cc] * (double)pl[cc*3 + v];
    *dst = (float)acc;
  }
}

// ---------------------------------------------------------------------------
// head: c = fcc_W @ vn_leaky(pooled, actc_Wd @ pooled) ; out [B,192]
// ---------------------------------------------------------------------------
__global__ __launch_bounds__(128) void head_kernel(
    const float* __restrict__ pooled, const float* __restrict__ Wa,
    const float* __restrict__ Wc, float* __restrict__ out) {
  __shared__ float xp[128*3], up[128*3];
  int b = blockIdx.x, c = threadIdx.x;
#pragma unroll
  for (int v = 0; v < 3; ++v) xp[c*3+v] = pooled[(size_t)b*384 + c*3 + v];
  __syncthreads();
  float a0 = 0.f, a1 = 0.f, a2 = 0.f;
  for (int j = 0; j < 128; ++j) {
    float w = Wa[c*128+j];
    a0 += w*xp[j*3+0]; a1 += w*xp[j*3+1]; a2 += w*xp[j*3+2];
  }
  float x0 = xp[c*3+0], x1 = xp[c*3+1], x2 = xp[c*3+2];
  float dot = x0*a0 + x1*a1 + x2*a2;
  float u0 = x0, u1 = x1, u2 = x2;
  if (dot < 0.0f) {
    float dsq = a0*a0 + a1*a1 + a2*a2;
    float s = dot / (dsq + 1e-6f);
    u0 = x0 - s*a0; u1 = x1 - s*a1; u2 = x2 - s*a2;
  }
  up[c*3+0] = u0; up[c*3+1] = u1; up[c*3+2] = u2;
  __syncthreads();
  if (c < 64) {
    float o0 = 0.f, o1 = 0.f, o2 = 0.f;
    for (int j = 0; j < 128; ++j) {
      float w = Wc[c*128+j];
      o0 += w*up[j*3+0]; o1 += w*up[j*3+1]; o2 += w*up[j*3+2];
    }
    out[(size_t)b*192 + c*3 + 0] = o0;
    out[(size_t)b*192 + c*3 + 1] = o1;
    out[(size_t)b*192 + c*3 + 2] = o2;
  }
}

// ---------------------------------------------------------------------------
extern "C" void kernel_launch(void* const* d_in, const int* in_sizes, int n_in,
                              void* d_out, int out_size, void* d_ws, size_t ws_size,
                              hipStream_t stream) {
  const float* pc    = (const float*)d_in[0];
  const float* cWf   = (const float*)d_in[1];
  const float* cWd   = (const float*)d_in[2];
  const float* pposW = (const float*)d_in[3];
  const float* fcW   = (const float*)d_in[4];
  const float* ba0   = (const float*)d_in[5];
  const float* bf0   = (const float*)d_in[6];
  const float* ba1   = (const float*)d_in[7];
  const float* bf1   = (const float*)d_in[8];
  const float* bscW  = (const float*)d_in[9];
  const float* pWd   = (const float*)d_in[10];
  const float* aWd   = (const float*)d_in[11];
  const float* fccW  = (const float*)d_in[12];
  float* out = (float*)d_out;
  char* ws = (char*)d_ws;
  const size_t MB = 1u << 20;
  const size_t KB = 1u << 10;
  // workspace (channel-fast activations [b][col][c]):
  int*      idxb   = (int*)(ws);                 // 1.31 MB
  float*    X1     = (float*)(ws + 2*MB);        // 48 MB  [B][NCOLS][256]
  float*    X2     = (float*)(ws + 52*MB);       // 48 MB
  float*    conv   = (float*)(ws + 52*MB);       // 12 MB [B][NCOLS][64] (aliases X2)
  float*    T      = (float*)(ws + 102*MB);      // 48 MB [B][NCOLS][256]
  float*    T2     = T;                          // 24 MB (aliases T low half)
  float*    Hn     = (float*)(ws + 152*MB);      // 24 MB [B][NCOLS][128]
  float*    pooled = (float*)(ws + 178*MB);      // 6 KB [B][384]
  double*   pv     = (double*)(ws + 178*MB + 16*KB);   // 256 KB [B][64][128]
  int*      pn     = (int*)(ws + 178*MB + 288*KB);     // 128 KB
  float*    biasA  = (float*)(ws + 178*MB + 448*KB);   // 12 KB [B][3][256]
  float*    biasS  = (float*)(ws + 178*MB + 512*KB);   // 6 KB  [B][3][128]
  _Float16* Wsp    = (_Float16*)(ws + 179*MB);   // 3.5 MB (hi at [i], lo at [i+WTOT])
  _Float16* WspLo  = Wsp + WTOT;

  wsplit_kernel<<<WTOT/256, 256, 0, stream>>>(fcW, ba0, bf0, ba1, bf1, bscW, pWd, Wsp);
  knn_kernel<<<NB*NPTS/4, 512, 0, stream>>>(pc, idxb);
  edgeconv_kernel<<<NB*NPTS/2, 128, 0, stream>>>(pc, idxb, cWf, cWd, pposW, conv);
  gemm_mfma<<<dim3(192, 2, NB), 256, 0, stream>>>(Wsp + WOFF_FC, WspLo + WOFF_FC,
      conv, nullptr, nullptr, X1, 64, 64, 64, 256, 0, 0, 0);

  float* Xin = X1; float* Xout = X2;
  for (int i = 0; i < 5; ++i) {
    const _Float16* a0h = Wsp   + WOFF_A0 + (size_t)i*65536;
    const _Float16* a0l = WspLo + WOFF_A0 + (size_t)i*65536;
    const _Float16* f0h = Wsp   + WOFF_F0 + (size_t)i*32768;
    const _Float16* f0l = WspLo + WOFF_F0 + (size_t)i*32768;
    const _Float16* f1h = Wsp   + WOFF_F1 + (size_t)i*16384;
    const _Float16* f1l = WspLo + WOFF_F1 + (size_t)i*16384;
    const _Float16* a1h = Wsp   + WOFF_A1 + (size_t)i*16384;
    const _Float16* a1l = WspLo + WOFF_A1 + (size_t)i*16384;
    const _Float16* sch = Wsp   + WOFF_SC + (size_t)i*32768;
    const _Float16* scl = WspLo + WOFF_SC + (size_t)i*32768;
    const _Float16* pwh = Wsp   + WOFF_PW + (size_t)i*16384;
    const _Float16* pwl = WspLo + WOFF_PW + (size_t)i*16384;
    int KA = (i == 0) ? 256 : 128;              // concat channels via bias for i>0
    const float* bA = (i == 0) ? nullptr : biasA;
    const float* bS = (i == 0) ? nullptr : biasS;
    const float* lp = (i == 0) ? nullptr : pooled;
    // FUSED: U = leaky(concat(X), a0 @ concat(X) (+biasA)) -> T
    gemm_leaky<2><<<dim3(NPTS/64, 2, NB), 256, 0, stream>>>(a0h, a0l, Xin, lp, bA, T,
        KA, 256, 256, 256, 256);
    // Hn = f0 @ U
    gemm_mfma<<<dim3(192,1,NB),256,0,stream>>>(f0h, f0l, T, nullptr, nullptr, Hn,
        256, 256, 256, 128, 0, 0, 0);
    // FUSED: U2 = leaky(Hn, a1 @ Hn) -> T2
    gemm_leaky<1><<<dim3(NPTS/32, 1, NB), 256, 0, stream>>>(a1h, a1l, Hn, nullptr, nullptr, T2,
        128, 128, 128, 128, 0);
    // DUAL: Xout = f1 @ U2 + sc @ concat(X) (+biasS)
    gemm_dual<<<dim3(192,1,NB),256,0,stream>>>(f1h, f1l, sch, scl, T2, Xin, bS, Xout,
        KA, 256, 128);
    // FUSED: Dm = pw @ net ; per-channel pool partials over 64-n chunks
    gemm_pool<<<dim3(NPTS/64,1,NB),256,0,stream>>>(pwh, pwl, Xout, pv, pn);
    // FUSED: pool stage-2 + bias for iteration i+1 (skipped on last iter)
    pool2bias_kernel<<<NB,128,0,stream>>>(pv, pn, Xout, pooled,
        ba0 + (size_t)(i+1 < 5 ? i+1 : 0)*65536,
        bscW + (size_t)(i+1 < 5 ? i+1 : 0)*32768,
        biasA, biasS, (i == 4) ? 1 : 0);
    if (i < 4) { float* tmp = Xin; Xin = Xout; Xout = tmp; }
  }
  head_kernel<<<NB,128,0,stream>>>(pooled, aWd, fccW, out);
}

// Round 20
// 1306.123 us; speedup vs baseline: 1.1081x; 1.1081x over previous
//
#include <hip/hip_runtime.h>
#include <hip/hip_bf16.h>
#include <math.h>

#define NPTS 4096
#define NB 4
#define KNN 20
#define NCOLS (3*NPTS)   // 12288
#define NEG_INF (-__builtin_huge_valf())
#define DNEG_INF (-__builtin_huge_val())

typedef _Float16 f16x8 __attribute__((ext_vector_type(8)));
typedef _Float16 f16x4 __attribute__((ext_vector_type(4)));
typedef float f32x4 __attribute__((ext_vector_type(4)));

// weight-split buffer geometry (elements)
#define WOFF_FC 0
#define WOFF_A0 16384
#define WOFF_F0 344064
#define WOFF_A1 507904
#define WOFF_F1 589824
#define WOFF_SC 671744
#define WOFF_PW 835584
#define WTOT    917504

// ---------------------------------------------------------------------------
// kNN in FP64 — 2 waves per row, 2-level selection (bit-identical ordering).
// ---------------------------------------------------------------------------
__global__ __launch_bounds__(512) void knn_kernel(const float* __restrict__ pc,
                                                  int* __restrict__ idx) {
  __shared__ float pts[NPTS*3];
  __shared__ double msv[2][8];
  __shared__ int    msn[2][8];
  int b = blockIdx.x >> 10;           // 1024 blocks per batch
  int rowblk = blockIdx.x & 1023;
  const float* pb = pc + (size_t)b*NPTS*3;
  for (int i = threadIdx.x; i < NPTS*3; i += 512) pts[i] = pb[i];
  __syncthreads();
  int wave = threadIdx.x >> 6;        // 0..7
  int lane = threadIdx.x & 63;
  int row  = wave >> 1;               // 0..3
  int half = wave & 1;
  int l128 = half*64 + lane;          // 0..127
  int n = rowblk*4 + row;
  double pn0 = pts[n*3+0], pn1 = pts[n*3+1], pn2 = pts[n*3+2];
  double sqn = pn0*pn0 + pn1*pn1 + pn2*pn2;
  double nd[32];
#pragma unroll
  for (int j = 0; j < 32; ++j) {
    int m = j*128 + l128;
    double q0 = pts[m*3+0], q1 = pts[m*3+1], q2 = pts[m*3+2];
    double inner = pn0*q0 + pn1*q1 + pn2*q2;
    double sqm = q0*q0 + q1*q1 + q2*q2;
    nd[j] = 2.0*inner - sqn - sqm;
  }
  double gm[2]; int gj[2];
#pragma unroll
  for (int g = 0; g < 2; ++g) {
    double v = nd[g*16]; int jb = g*16;
#pragma unroll
    for (int jj = 1; jj < 16; ++jj) {
      int j = g*16 + jj;
      bool take = nd[j] > v;
      v = take ? nd[j] : v;
      jb = take ? j : jb;
    }
    gm[g] = v; gj[g] = jb;
  }
  int* orow = idx + ((size_t)b*NPTS + n)*KNN;
  for (int t = 0; t < KNN; ++t) {
    double bv = gm[0]; int bj = gj[0];
    if (gm[1] > bv) { bv = gm[1]; bj = gj[1]; }
    int bm = bj*128 + l128;
#pragma unroll
    for (int s = 1; s < 64; s <<= 1) {
      double ov = __shfl_xor(bv, s, 64);
      int om = __shfl_xor(bm, s, 64);
      bool take = (ov > bv) || (ov == bv && om < bm);
      bv = take ? ov : bv;
      bm = take ? om : bm;
    }
    if (lane == 0) { msv[t&1][wave] = bv; msn[t&1][wave] = bm; }
    __syncthreads();
    {
      double pv = msv[t&1][wave^1]; int pm = msn[t&1][wave^1];
      bool take = (pv > bv) || (pv == bv && pm < bm);
      bv = take ? pv : bv;
      bm = take ? pm : bm;
    }
    if (half == 0 && lane == 0) orow[t] = bm;
    if (t < KNN-1) {
      int vic_l128 = bm & 127;
      int jw = bm >> 7;
      int vic_half = vic_l128 >> 6;
      if (vic_half == half) {           // wave-uniform: only victim's wave pays
        bool iswl = (l128 == vic_l128);
        int gw = jw >> 4;
#define REBUILD(G) { \
  _Pragma("unroll") \
  for (int jj = 0; jj < 16; ++jj) { \
    int j = (G)*16 + jj; \
    if (iswl && j == jw) nd[j] = DNEG_INF; \
  } \
  double v = nd[(G)*16]; int jb = (G)*16; \
  _Pragma("unroll") \
  for (int jj = 1; jj < 16; ++jj) { \
    int j = (G)*16 + jj; \
    bool take = nd[j] > v; \
    v = take ? nd[j] : v; \
    jb = take ? j : jb; \
  } \
  gm[G] = v; gj[G] = jb; \
}
        if (gw == 0) REBUILD(0)
        else         REBUILD(1)
#undef REBUILD
      }
    }
  }
}

// ---------------------------------------------------------------------------
// Edge conv v3 — kk chunks of ECH=5, running argmax (bit-identical).
// fp32 compute, fp64 final dot+compare. 2 waves per 128-thread block.
// Output conv[b][v*N+n][c], c<64.
// ---------------------------------------------------------------------------
#define ECH 5
__global__ __launch_bounds__(128) void edgeconv_kernel(
    const float* __restrict__ pc, const int* __restrict__ knnidx,
    const float* __restrict__ Wf, const float* __restrict__ Wd,
    const float* __restrict__ Wp, float* __restrict__ outp) {
  __shared__ float xls[2*ECH*3*64];   // per wave: x[(v*ECH+kc)*64 + c]
  int wave = threadIdx.x >> 6, lane = threadIdx.x & 63;
  int pid0 = blockIdx.x * 2;
  int b = pid0 >> 12;
  int n = (pid0 & (NPTS-1)) + wave;
  const float* pb = pc + (size_t)b*NPTS*3;
  int c = lane;
  float wrow[64];
#pragma unroll
  for (int j = 0; j < 64; ++j) wrow[j] = Wp[c*64 + j];
  float wf0 = Wf[c*3+0], wf1 = Wf[c*3+1], wf2 = Wf[c*3+2];
  float wd0 = Wd[c*3+0], wd1 = Wd[c*3+1], wd2 = Wd[c*3+2];
  float f9[9];
#pragma unroll
  for (int i = 0; i < 9; ++i) f9[i] = 0.0f;
  if (lane < KNN) {
    int j = knnidx[((size_t)b*NPTS + n)*KNN + lane];
    float q0 = pb[j*3+0], q1 = pb[j*3+1], q2 = pb[j*3+2];
    float x0 = pb[n*3+0], x1 = pb[n*3+1], x2 = pb[n*3+2];
    f9[0] = q0-x0; f9[1] = q1-x1; f9[2] = q2-x2;
    f9[3] = x0;    f9[4] = x1;    f9[5] = x2;
    f9[6] = q1*x2 - q2*x1;
    f9[7] = q2*x0 - q0*x2;
    f9[8] = q0*x1 - q1*x0;
  }
  float* xw = &xls[wave*ECH*3*64];
  double bdot = DNEG_INF;
  float bx0 = 0.f, bx1 = 0.f, bx2 = 0.f;
  for (int k0 = 0; k0 < KNN; k0 += ECH) {
    for (int kc = 0; kc < ECH; ++kc) {
      int kk = k0 + kc;
      float fch[9];
#pragma unroll
      for (int i = 0; i < 9; ++i) fch[i] = __shfl(f9[i], kk, 64);
      float fv[3], dv[3];
#pragma unroll
      for (int v = 0; v < 3; ++v) {
        fv[v] = wf0*fch[v] + wf1*fch[3+v] + wf2*fch[6+v];
        dv[v] = wd0*fch[v] + wd1*fch[3+v] + wd2*fch[6+v];
      }
      float dot = fv[0]*dv[0] + fv[1]*dv[1] + fv[2]*dv[2];
      if (dot < 0.0f) {
        float dsq = dv[0]*dv[0] + dv[1]*dv[1] + dv[2]*dv[2];
        float s = dot / (dsq + 1e-6f);
        fv[0] -= s*dv[0]; fv[1] -= s*dv[1]; fv[2] -= s*dv[2];
      }
      xw[(0*ECH+kc)*64 + c] = fv[0];
      xw[(1*ECH+kc)*64 + c] = fv[1];
      xw[(2*ECH+kc)*64 + c] = fv[2];
    }
    for (int kc = 0; kc < ECH; ++kc) {
      float a0 = 0.f, a1 = 0.f, a2 = 0.f;
#pragma unroll
      for (int j = 0; j < 64; j += 4) {
        float4 v0 = *(const float4*)&xw[(0*ECH+kc)*64 + j];
        float4 v1 = *(const float4*)&xw[(1*ECH+kc)*64 + j];
        float4 v2 = *(const float4*)&xw[(2*ECH+kc)*64 + j];
        a0 += wrow[j]*v0.x + wrow[j+1]*v0.y + wrow[j+2]*v0.z + wrow[j+3]*v0.w;
        a1 += wrow[j]*v1.x + wrow[j+1]*v1.y + wrow[j+2]*v1.z + wrow[j+3]*v1.w;
        a2 += wrow[j]*v2.x + wrow[j+1]*v2.y + wrow[j+2]*v2.z + wrow[j+3]*v2.w;
      }
      float xc0 = xw[(0*ECH+kc)*64 + c];
      float xc1 = xw[(1*ECH+kc)*64 + c];
      float xc2 = xw[(2*ECH+kc)*64 + c];
      double dd = (double)xc0*a0 + (double)xc1*a1 + (double)xc2*a2;
      bool take = dd > bdot;          // kk ascending + strict > = first max
      bdot = take ? dd : bdot;
      bx0 = take ? xc0 : bx0;
      bx1 = take ? xc1 : bx1;
      bx2 = take ? xc2 : bx2;
    }
  }
  outp[((size_t)b*NCOLS + 0*NPTS + n)*64 + c] = bx0;
  outp[((size_t)b*NCOLS + 1*NPTS + n)*64 + c] = bx1;
  outp[((size_t)b*NCOLS + 2*NPTS + n)*64 + c] = bx2;
}

// ---------------------------------------------------------------------------
// one-shot weight split: fp32 -> f16 hi (at [i]) + f16 lo (at [i+WTOT])
// ---------------------------------------------------------------------------
__global__ __launch_bounds__(256) void wsplit_kernel(
    const float* __restrict__ fc, const float* __restrict__ a0,
    const float* __restrict__ f0, const float* __restrict__ a1,
    const float* __restrict__ f1, const float* __restrict__ sc,
    const float* __restrict__ pw, _Float16* __restrict__ outp) {
  int i = blockIdx.x*256 + threadIdx.x;
  const float* src; int off;
  if      (i < WOFF_A0) { src = fc; off = WOFF_FC; }
  else if (i < WOFF_F0) { src = a0; off = WOFF_A0; }
  else if (i < WOFF_A1) { src = f0; off = WOFF_F0; }
  else if (i < WOFF_F1) { src = a1; off = WOFF_A1; }
  else if (i < WOFF_SC) { src = f1; off = WOFF_F1; }
  else if (i < WOFF_PW) { src = sc; off = WOFF_SC; }
  else                  { src = pw; off = WOFF_PW; }
  float w = src[i - off];
  _Float16 h = (_Float16)w;
  outp[i] = h;
  outp[i + WTOT] = (_Float16)(w - (float)h);
}

// ---------------------------------------------------------------------------
// merged concat-as-bias: biasA (a0 cols 128..255) and biasS (sc cols 128..255)
// ---------------------------------------------------------------------------
__global__ __launch_bounds__(256) void bias2_kernel(
    const float* __restrict__ Wa0, const float* __restrict__ Wsc,
    const float* __restrict__ pooled,
    float* __restrict__ biasA, float* __restrict__ biasS) {
  int id = blockIdx.x*256 + threadIdx.x;   // NB*3*256 + NB*3*128 = 4608
  if (id >= NB*3*384) return;
  const float* W; float* dst; int Cout; int idx;
  if (id < NB*3*256) { W = Wa0; dst = biasA; Cout = 256; idx = id; }
  else               { W = Wsc; dst = biasS; Cout = 128; idx = id - NB*3*256; }
  int co = idx % Cout; int t = idx / Cout;
  int v = t % 3; int b = t / 3;
  double acc = 0.0;
  const float* wr = W + (size_t)co*256 + 128;
  const float* pp = pooled + (size_t)b*384 + v;
#pragma unroll 4
  for (int c = 0; c < 128; ++c)
    acc += (double)wr[c] * (double)pp[c*3];
  dst[idx] = (float)acc;
}

// ---------------------------------------------------------------------------
// MFMA GEMM — BM=64 x BN=128 tile. fp16x2 split, pre-split W.
// ---------------------------------------------------------------------------
#define LDP 40
__global__ __launch_bounds__(256) void gemm_mfma(
    const _Float16* __restrict__ Wh, const _Float16* __restrict__ Wl,
    const float* __restrict__ X, const float* __restrict__ Z,
    const float* __restrict__ bias, float* __restrict__ Y,
    int Cin, int Wstride, int ldX, int ldY, int ldZ, int addZ, int Cbias) {
  __shared__ __align__(16) _Float16 Ah[64*LDP];
  __shared__ __align__(16) _Float16 Al[64*LDP];
  __shared__ __align__(16) _Float16 Bh[128*LDP];
  __shared__ __align__(16) _Float16 Bl[128*LDP];
  int b = blockIdx.z;
  int sp0 = blockIdx.x * 64;
  int co0 = blockIdx.y * 128;
  const float* Xb = X + ((size_t)b*NCOLS + sp0) * ldX;
  int t = threadIdx.x;
  int arow = t >> 2, akoff = (t & 3) * 8;
  int brow = t >> 1, bkoff = (t & 1) * 16;
  int wid = t >> 6, lane = t & 63;
  int wr = (wid >> 1) * 32, wc = (wid & 1) * 64;
  int lrow = lane & 15, lk = (lane >> 4) * 8;
  f32x4 acc[2][4];
#pragma unroll
  for (int f = 0; f < 2; ++f)
#pragma unroll
    for (int g = 0; g < 4; ++g)
#pragma unroll
      for (int r = 0; r < 4; ++r) acc[f][g][r] = 0.0f;

  for (int k0 = 0; k0 < Cin; k0 += 32) {
    const float* xs = Xb + (size_t)arow*ldX + k0 + akoff;
    float xv[8];
    *(float4*)&xv[0] = *(const float4*)&xs[0];
    *(float4*)&xv[4] = *(const float4*)&xs[4];
    _Float16 xh[8], xl[8];
#pragma unroll
    for (int j = 0; j < 8; ++j) {
      _Float16 h = (_Float16)xv[j];
      xh[j] = h; xl[j] = (_Float16)(xv[j] - (float)h);
    }
    *(f16x8*)&Ah[arow*LDP + akoff] = *(f16x8*)&xh[0];
    *(f16x8*)&Al[arow*LDP + akoff] = *(f16x8*)&xl[0];
    const _Float16* whs = Wh + (size_t)(co0 + brow)*Wstride + k0 + bkoff;
    const _Float16* wls = Wl + (size_t)(co0 + brow)*Wstride + k0 + bkoff;
    *(f16x8*)&Bh[brow*LDP + bkoff]     = *(const f16x8*)&whs[0];
    *(f16x8*)&Bh[brow*LDP + bkoff + 8] = *(const f16x8*)&whs[8];
    *(f16x8*)&Bl[brow*LDP + bkoff]     = *(const f16x8*)&wls[0];
    *(f16x8*)&Bl[brow*LDP + bkoff + 8] = *(const f16x8*)&wls[8];
    __syncthreads();
    f16x8 ah[2], al[2], bh[4], bl[4];
#pragma unroll
    for (int f = 0; f < 2; ++f) {
      ah[f] = *(f16x8*)&Ah[(wr + f*16 + lrow)*LDP + lk];
      al[f] = *(f16x8*)&Al[(wr + f*16 + lrow)*LDP + lk];
    }
#pragma unroll
    for (int g = 0; g < 4; ++g) {
      bh[g] = *(f16x8*)&Bh[(wc + g*16 + lrow)*LDP + lk];
      bl[g] = *(f16x8*)&Bl[(wc + g*16 + lrow)*LDP + lk];
    }
#pragma unroll
    for (int f = 0; f < 2; ++f)
#pragma unroll
      for (int g = 0; g < 4; ++g) {
        acc[f][g] = __builtin_amdgcn_mfma_f32_16x16x32_f16(ah[f], bh[g], acc[f][g], 0, 0, 0);
        acc[f][g] = __builtin_amdgcn_mfma_f32_16x16x32_f16(ah[f], bl[g], acc[f][g], 0, 0, 0);
        acc[f][g] = __builtin_amdgcn_mfma_f32_16x16x32_f16(al[f], bh[g], acc[f][g], 0, 0, 0);
      }
    __syncthreads();
  }
  int lr0 = (lane >> 4) * 4, lc = lane & 15;
  float badd[4] = {0.f, 0.f, 0.f, 0.f};
  if (bias) {
    int v = sp0 >> 12;
    const float* brow2 = bias + ((size_t)b*3 + v)*Cbias;
#pragma unroll
    for (int g = 0; g < 4; ++g) badd[g] = brow2[co0 + wc + g*16 + lc];
  }
#pragma unroll
  for (int f = 0; f < 2; ++f)
#pragma unroll
    for (int g = 0; g < 4; ++g)
#pragma unroll
      for (int r = 0; r < 4; ++r) {
        int sp = sp0 + wr + f*16 + lr0 + r;
        int co = co0 + wc + g*16 + lc;
        float val = acc[f][g][r] + badd[g];
        if (addZ) val += Z[((size_t)b*NCOLS + sp)*ldZ + co];
        Y[((size_t)b*NCOLS + sp)*ldY + co] = val;
      }
}

// ---------------------------------------------------------------------------
// DUAL GEMM: Y = W1 @ X1 + W2 @ X2 (+bias).
// ---------------------------------------------------------------------------
__global__ __launch_bounds__(256) void gemm_dual(
    const _Float16* __restrict__ W1h, const _Float16* __restrict__ W1l,
    const _Float16* __restrict__ W2h, const _Float16* __restrict__ W2l,
    const float* __restrict__ X1, const float* __restrict__ X2s,
    const float* __restrict__ bias, float* __restrict__ Y,
    int K2, int ldY, int Cbias) {
  __shared__ __align__(16) _Float16 Ah[64*LDP];
  __shared__ __align__(16) _Float16 Al[64*LDP];
  __shared__ __align__(16) _Float16 Bh[128*LDP];
  __shared__ __align__(16) _Float16 Bl[128*LDP];
  int b = blockIdx.z;
  int sp0 = blockIdx.x * 64;
  int co0 = blockIdx.y * 128;
  int t = threadIdx.x;
  int arow = t >> 2, akoff = (t & 3) * 8;
  int brow = t >> 1, bkoff = (t & 1) * 16;
  int wid = t >> 6, lane = t & 63;
  int wr = (wid >> 1) * 32, wc = (wid & 1) * 64;
  int lrow = lane & 15, lk = (lane >> 4) * 8;
  f32x4 acc[2][4];
#pragma unroll
  for (int f = 0; f < 2; ++f)
#pragma unroll
    for (int g = 0; g < 4; ++g)
#pragma unroll
      for (int r = 0; r < 4; ++r) acc[f][g][r] = 0.0f;

  int Ktot = 128 + K2;
  for (int k0 = 0; k0 < Ktot; k0 += 32) {
    const float* xs;
    const _Float16 *whs, *wls;
    if (k0 < 128) {
      xs  = X1 + ((size_t)b*NCOLS + sp0 + arow)*128 + k0 + akoff;
      whs = W1h + (size_t)(co0 + brow)*128 + k0 + bkoff;
      wls = W1l + (size_t)(co0 + brow)*128 + k0 + bkoff;
    } else {
      xs  = X2s + ((size_t)b*NCOLS + sp0 + arow)*256 + (k0-128) + akoff;
      whs = W2h + (size_t)(co0 + brow)*256 + (k0-128) + bkoff;
      wls = W2l + (size_t)(co0 + brow)*256 + (k0-128) + bkoff;
    }
    float xv[8];
    *(float4*)&xv[0] = *(const float4*)&xs[0];
    *(float4*)&xv[4] = *(const float4*)&xs[4];
    _Float16 xh[8], xl[8];
#pragma unroll
    for (int j = 0; j < 8; ++j) {
      _Float16 h = (_Float16)xv[j];
      xh[j] = h; xl[j] = (_Float16)(xv[j] - (float)h);
    }
    *(f16x8*)&Ah[arow*LDP + akoff] = *(f16x8*)&xh[0];
    *(f16x8*)&Al[arow*LDP + akoff] = *(f16x8*)&xl[0];
    *(f16x8*)&Bh[brow*LDP + bkoff]     = *(const f16x8*)&whs[0];
    *(f16x8*)&Bh[brow*LDP + bkoff + 8] = *(const f16x8*)&whs[8];
    *(f16x8*)&Bl[brow*LDP + bkoff]     = *(const f16x8*)&wls[0];
    *(f16x8*)&Bl[brow*LDP + bkoff + 8] = *(const f16x8*)&wls[8];
    __syncthreads();
    f16x8 ah[2], al[2], bh[4], bl[4];
#pragma unroll
    for (int f = 0; f < 2; ++f) {
      ah[f] = *(f16x8*)&Ah[(wr + f*16 + lrow)*LDP + lk];
      al[f] = *(f16x8*)&Al[(wr + f*16 + lrow)*LDP + lk];
    }
#pragma unroll
    for (int g = 0; g < 4; ++g) {
      bh[g] = *(f16x8*)&Bh[(wc + g*16 + lrow)*LDP + lk];
      bl[g] = *(f16x8*)&Bl[(wc + g*16 + lrow)*LDP + lk];
    }
#pragma unroll
    for (int f = 0; f < 2; ++f)
#pragma unroll
      for (int g = 0; g < 4; ++g) {
        acc[f][g] = __builtin_amdgcn_mfma_f32_16x16x32_f16(ah[f], bh[g], acc[f][g], 0, 0, 0);
        acc[f][g] = __builtin_amdgcn_mfma_f32_16x16x32_f16(ah[f], bl[g], acc[f][g], 0, 0, 0);
        acc[f][g] = __builtin_amdgcn_mfma_f32_16x16x32_f16(al[f], bh[g], acc[f][g], 0, 0, 0);
      }
    __syncthreads();
  }
  int lr0 = (lane >> 4) * 4, lc = lane & 15;
  float badd[4] = {0.f, 0.f, 0.f, 0.f};
  if (bias) {
    int v = sp0 >> 12;
    const float* brow2 = bias + ((size_t)b*3 + v)*Cbias;
#pragma unroll
    for (int g = 0; g < 4; ++g) badd[g] = brow2[co0 + wc + g*16 + lc];
  }
#pragma unroll
  for (int f = 0; f < 2; ++f)
#pragma unroll
    for (int g = 0; g < 4; ++g)
#pragma unroll
      for (int r = 0; r < 4; ++r) {
        int sp = sp0 + wr + f*16 + lr0 + r;
        int co = co0 + wc + g*16 + lc;
        Y[((size_t)b*NCOLS + sp)*ldY + co] = acc[f][g][r] + badd[g];
      }
}

// ---------------------------------------------------------------------------
// FUSED GEMM + vn_leaky.
// ---------------------------------------------------------------------------
template<int FM>
__global__ __launch_bounds__(256) void gemm_leaky(
    const _Float16* __restrict__ Wh, const _Float16* __restrict__ Wl,
    const float* __restrict__ X, const float* __restrict__ pooled,
    const float* __restrict__ bias, float* __restrict__ Y,
    int Cin, int Wstride, int ldX, int ldY, int Cbias) {
  constexpr int BM = FM*32;
  __shared__ __align__(16) _Float16 Ah[BM*LDP];
  __shared__ __align__(16) _Float16 Al[BM*LDP];
  __shared__ __align__(16) _Float16 Bh[128*LDP];
  __shared__ __align__(16) _Float16 Bl[128*LDP];
  int b = blockIdx.z;
  int n0 = blockIdx.x * BM;
  int co0 = blockIdx.y * 128;
  int t = threadIdx.x;
  constexpr int APT = BM/8;
  constexpr int TPR = 32/APT;
  int arow = t / TPR, akoff = (t % TPR) * APT;
  int brow = t >> 1, bkoff = (t & 1) * 16;
  int wid = t >> 6, lane = t & 63;
  int wr = (wid >> 1) * (BM/2), wc = (wid & 1) * 64;
  int lrow = lane & 15, lk = (lane >> 4) * 8;
  f32x4 acc[3][FM][4];
#pragma unroll
  for (int v = 0; v < 3; ++v)
#pragma unroll
    for (int f = 0; f < FM; ++f)
#pragma unroll
      for (int g = 0; g < 4; ++g)
#pragma unroll
        for (int r = 0; r < 4; ++r) acc[v][f][g][r] = 0.0f;

  for (int v = 0; v < 3; ++v) {
    const float* Xb = X + ((size_t)b*NCOLS + (size_t)v*NPTS + n0) * ldX;
    for (int k0 = 0; k0 < Cin; k0 += 32) {
      const float* xs = Xb + (size_t)arow*ldX + k0 + akoff;
      float xv[APT];
#pragma unroll
      for (int j = 0; j < APT; j += 4)
        *(float4*)&xv[j] = *(const float4*)&xs[j];
      _Float16 xh[APT], xl[APT];
#pragma unroll
      for (int j = 0; j < APT; ++j) {
        _Float16 h = (_Float16)xv[j];
        xh[j] = h; xl[j] = (_Float16)(xv[j] - (float)h);
      }
      if (APT == 8) {
        *(f16x8*)&Ah[arow*LDP + akoff] = *(f16x8*)&xh[0];
        *(f16x8*)&Al[arow*LDP + akoff] = *(f16x8*)&xl[0];
      } else {
        *(f16x4*)&Ah[arow*LDP + akoff] = *(f16x4*)&xh[0];
        *(f16x4*)&Al[arow*LDP + akoff] = *(f16x4*)&xl[0];
      }
      const _Float16* whs = Wh + (size_t)(co0 + brow)*Wstride + k0 + bkoff;
      const _Float16* wls = Wl + (size_t)(co0 + brow)*Wstride + k0 + bkoff;
      *(f16x8*)&Bh[brow*LDP + bkoff]     = *(const f16x8*)&whs[0];
      *(f16x8*)&Bh[brow*LDP + bkoff + 8] = *(const f16x8*)&whs[8];
      *(f16x8*)&Bl[brow*LDP + bkoff]     = *(const f16x8*)&wls[0];
      *(f16x8*)&Bl[brow*LDP + bkoff + 8] = *(const f16x8*)&wls[8];
      __syncthreads();
      f16x8 ah[FM], al[FM], bh[4], bl[4];
#pragma unroll
      for (int f = 0; f < FM; ++f) {
        ah[f] = *(f16x8*)&Ah[(wr + f*16 + lrow)*LDP + lk];
        al[f] = *(f16x8*)&Al[(wr + f*16 + lrow)*LDP + lk];
      }
#pragma unroll
      for (int g = 0; g < 4; ++g) {
        bh[g] = *(f16x8*)&Bh[(wc + g*16 + lrow)*LDP + lk];
        bl[g] = *(f16x8*)&Bl[(wc + g*16 + lrow)*LDP + lk];
      }
#pragma unroll
      for (int f = 0; f < FM; ++f)
#pragma unroll
        for (int g = 0; g < 4; ++g) {
          acc[v][f][g] = __builtin_amdgcn_mfma_f32_16x16x32_f16(ah[f], bh[g], acc[v][f][g], 0, 0, 0);
          acc[v][f][g] = __builtin_amdgcn_mfma_f32_16x16x32_f16(ah[f], bl[g], acc[v][f][g], 0, 0, 0);
          acc[v][f][g] = __builtin_amdgcn_mfma_f32_16x16x32_f16(al[f], bh[g], acc[v][f][g], 0, 0, 0);
        }
      __syncthreads();
    }
  }
  int lr0 = (lane >> 4) * 4, lc = lane & 15;
  float badd[3][4];
#pragma unroll
  for (int v = 0; v < 3; ++v)
#pragma unroll
    for (int g = 0; g < 4; ++g) {
      badd[v][g] = bias ? bias[((size_t)b*3 + v)*Cbias + co0 + wc + g*16 + lc] : 0.0f;
    }
  bool xfromX = (pooled == nullptr) || (co0 < 128);
#pragma unroll
  for (int f = 0; f < FM; ++f)
#pragma unroll
    for (int g = 0; g < 4; ++g)
#pragma unroll
      for (int r = 0; r < 4; ++r) {
        int n = n0 + wr + f*16 + lr0 + r;
        int co = co0 + wc + g*16 + lc;
        float x0, x1, x2;
        if (xfromX) {
          x0 = X[((size_t)b*NCOLS + 0*NPTS + n)*ldX + co];
          x1 = X[((size_t)b*NCOLS + 1*NPTS + n)*ldX + co];
          x2 = X[((size_t)b*NCOLS + 2*NPTS + n)*ldX + co];
        } else {
          const float* pp = pooled + (size_t)b*384 + (co - 128)*3;
          x0 = pp[0]; x1 = pp[1]; x2 = pp[2];
        }
        float d0 = acc[0][f][g][r] + badd[0][g];
        float d1 = acc[1][f][g][r] + badd[1][g];
        float d2 = acc[2][f][g][r] + badd[2][g];
        float dot = x0*d0 + x1*d1 + x2*d2;
        float u0 = x0, u1 = x1, u2 = x2;
        if (dot < 0.0f) {
          float dsq = d0*d0 + d1*d1 + d2*d2;
          float s = dot / (dsq + 1e-6f);
          u0 = x0 - s*d0; u1 = x1 - s*d1; u2 = x2 - s*d2;
        }
        Y[((size_t)b*NCOLS + 0*NPTS + n)*ldY + co] = u0;
        Y[((size_t)b*NCOLS + 1*NPTS + n)*ldY + co] = u1;
        Y[((size_t)b*NCOLS + 2*NPTS + n)*ldY + co] = u2;
      }
}

// ---------------------------------------------------------------------------
// FUSED pw-GEMM + pool-over-N partial argmax.
// ---------------------------------------------------------------------------
__global__ __launch_bounds__(256) void gemm_pool(
    const _Float16* __restrict__ Wh, const _Float16* __restrict__ Wl,
    const float* __restrict__ X,
    double* __restrict__ pv, int* __restrict__ pn) {
  __shared__ __align__(16) _Float16 Ah[64*LDP];
  __shared__ __align__(16) _Float16 Al[64*LDP];
  __shared__ __align__(16) _Float16 Bh[128*LDP];
  __shared__ __align__(16) _Float16 Bl[128*LDP];
  int b = blockIdx.z;
  int n0 = blockIdx.x * 64;
  int t = threadIdx.x;
  int arow = t >> 2, akoff = (t & 3) * 8;
  int brow = t >> 1, bkoff = (t & 1) * 16;
  int wid = t >> 6, lane = t & 63;
  int wr = (wid >> 1) * 32, wc = (wid & 1) * 64;
  int lrow = lane & 15, lk = (lane >> 4) * 8;
  f32x4 acc[3][2][4];
#pragma unroll
  for (int v = 0; v < 3; ++v)
#pragma unroll
    for (int f = 0; f < 2; ++f)
#pragma unroll
      for (int g = 0; g < 4; ++g)
#pragma unroll
        for (int r = 0; r < 4; ++r) acc[v][f][g][r] = 0.0f;

  for (int v = 0; v < 3; ++v) {
    const float* Xb = X + ((size_t)b*NCOLS + (size_t)v*NPTS + n0) * 256;
    for (int k0 = 0; k0 < 128; k0 += 32) {
      const float* xs = Xb + (size_t)arow*256 + k0 + akoff;
      float xv[8];
      *(float4*)&xv[0] = *(const float4*)&xs[0];
      *(float4*)&xv[4] = *(const float4*)&xs[4];
      _Float16 xh[8], xl[8];
#pragma unroll
      for (int j = 0; j < 8; ++j) {
        _Float16 h = (_Float16)xv[j];
        xh[j] = h; xl[j] = (_Float16)(xv[j] - (float)h);
      }
      *(f16x8*)&Ah[arow*LDP + akoff] = *(f16x8*)&xh[0];
      *(f16x8*)&Al[arow*LDP + akoff] = *(f16x8*)&xl[0];
      const _Float16* whs = Wh + (size_t)brow*128 + k0 + bkoff;
      const _Float16* wls = Wl + (size_t)brow*128 + k0 + bkoff;
      *(f16x8*)&Bh[brow*LDP + bkoff]     = *(const f16x8*)&whs[0];
      *(f16x8*)&Bh[brow*LDP + bkoff + 8] = *(const f16x8*)&whs[8];
      *(f16x8*)&Bl[brow*LDP + bkoff]     = *(const f16x8*)&wls[0];
      *(f16x8*)&Bl[brow*LDP + bkoff + 8] = *(const f16x8*)&wls[8];
      __syncthreads();
      f16x8 ah[2], al[2], bh[4], bl[4];
#pragma unroll
      for (int f = 0; f < 2; ++f) {
        ah[f] = *(f16x8*)&Ah[(wr + f*16 + lrow)*LDP + lk];
        al[f] = *(f16x8*)&Al[(wr + f*16 + lrow)*LDP + lk];
      }
#pragma unroll
      for (int g = 0; g < 4; ++g) {
        bh[g] = *(f16x8*)&Bh[(wc + g*16 + lrow)*LDP + lk];
        bl[g] = *(f16x8*)&Bl[(wc + g*16 + lrow)*LDP + lk];
      }
#pragma unroll
      for (int f = 0; f < 2; ++f)
#pragma unroll
        for (int g = 0; g < 4; ++g) {
          acc[v][f][g] = __builtin_amdgcn_mfma_f32_16x16x32_f16(ah[f], bh[g], acc[v][f][g], 0, 0, 0);
          acc[v][f][g] = __builtin_amdgcn_mfma_f32_16x16x32_f16(ah[f], bl[g], acc[v][f][g], 0, 0, 0);
          acc[v][f][g] = __builtin_amdgcn_mfma_f32_16x16x32_f16(al[f], bh[g], acc[v][f][g], 0, 0, 0);
        }
      __syncthreads();
    }
  }
  int lr0 = (lane >> 4) * 4, lc = lane & 15;
  double bestv[4]; int bestn[4];
#pragma unroll
  for (int g = 0; g < 4; ++g) { bestv[g] = DNEG_INF; bestn[g] = 0x7fffffff; }
#pragma unroll
  for (int f = 0; f < 2; ++f)
#pragma unroll
    for (int r = 0; r < 4; ++r) {
      int n = n0 + wr + f*16 + lr0 + r;
#pragma unroll
      for (int g = 0; g < 4; ++g) {
        int co = wc + g*16 + lc;
        double dot =
            (double)X[((size_t)b*NCOLS + 0*NPTS + n)*256 + co] * (double)acc[0][f][g][r]
          + (double)X[((size_t)b*NCOLS + 1*NPTS + n)*256 + co] * (double)acc[1][f][g][r]
          + (double)X[((size_t)b*NCOLS + 2*NPTS + n)*256 + co] * (double)acc[2][f][g][r];
        bool take = (dot > bestv[g]) || (dot == bestv[g] && n < bestn[g]);
        bestv[g] = take ? dot : bestv[g];
        bestn[g] = take ? n : bestn[g];
      }
    }
#pragma unroll
  for (int s = 16; s < 64; s <<= 1) {
#pragma unroll
    for (int g = 0; g < 4; ++g) {
      double ov = __shfl_xor(bestv[g], s, 64);
      int on = __shfl_xor(bestn[g], s, 64);
      bool take = (ov > bestv[g]) || (ov == bestv[g] && on < bestn[g]);
      bestv[g] = take ? ov : bestv[g];
      bestn[g] = take ? on : bestn[g];
    }
  }
  double* cdv = (double*)Ah;
  int*    cdn = (int*)Bh;
  if (lane < 16) {
#pragma unroll
    for (int g = 0; g < 4; ++g) {
      cdv[(wid*4 + g)*16 + lane] = bestv[g];
      cdn[(wid*4 + g)*16 + lane] = bestn[g];
    }
  }
  __syncthreads();
  if (t < 128) {
    int c = t;
    int wq = c >> 6;
    int g = (c >> 4) & 3, l2 = c & 15;
    double v0 = cdv[((wq)*4 + g)*16 + l2];   int n0v = cdn[((wq)*4 + g)*16 + l2];
    double v1 = cdv[((wq+2)*4 + g)*16 + l2]; int n1v = cdn[((wq+2)*4 + g)*16 + l2];
    bool take = (v1 > v0) || (v1 == v0 && n1v < n0v);
    double bv = take ? v1 : v0;
    int bn = take ? n1v : n0v;
    pv[((size_t)b*64 + blockIdx.x)*128 + c] = bv;
    pn[((size_t)b*64 + blockIdx.x)*128 + c] = bn;
  }
}

// stage 2: per (b,c) merge 64 chunk partials, gather.
__global__ __launch_bounds__(128) void pool2_kernel(
    const double* __restrict__ pv, const int* __restrict__ pn,
    const float* __restrict__ Net, float* __restrict__ pooled, int ldN) {
  int b = blockIdx.x, c = threadIdx.x;
  double bv = DNEG_INF; int bn = 0x7fffffff;
  for (int ch = 0; ch < 64; ++ch) {
    double v = pv[((size_t)b*64 + ch)*128 + c];
    int nn = pn[((size_t)b*64 + ch)*128 + c];
    if (v > bv || (v == bv && nn < bn)) { bv = v; bn = nn; }
  }
#pragma unroll
  for (int v = 0; v < 3; ++v)
    pooled[(size_t)b*384 + c*3 + v] = Net[((size_t)b*NCOLS + v*NPTS + bn)*ldN + c];
}

// ---------------------------------------------------------------------------
// head: c = fcc_W @ vn_leaky(pooled, actc_Wd @ pooled) ; out [B,192]
// ---------------------------------------------------------------------------
__global__ __launch_bounds__(128) void head_kernel(
    const float* __restrict__ pooled, const float* __restrict__ Wa,
    const float* __restrict__ Wc, float* __restrict__ out) {
  __shared__ float xp[128*3], up[128*3];
  int b = blockIdx.x, c = threadIdx.x;
#pragma unroll
  for (int v = 0; v < 3; ++v) xp[c*3+v] = pooled[(size_t)b*384 + c*3 + v];
  __syncthreads();
  float a0 = 0.f, a1 = 0.f, a2 = 0.f;
  for (int j = 0; j < 128; ++j) {
    float w = Wa[c*128+j];
    a0 += w*xp[j*3+0]; a1 += w*xp[j*3+1]; a2 += w*xp[j*3+2];
  }
  float x0 = xp[c*3+0], x1 = xp[c*3+1], x2 = xp[c*3+2];
  float dot = x0*a0 + x1*a1 + x2*a2;
  float u0 = x0, u1 = x1, u2 = x2;
  if (dot < 0.0f) {
    float dsq = a0*a0 + a1*a1 + a2*a2;
    float s = dot / (dsq + 1e-6f);
    u0 = x0 - s*a0; u1 = x1 - s*a1; u2 = x2 - s*a2;
  }
  up[c*3+0] = u0; up[c*3+1] = u1; up[c*3+2] = u2;
  __syncthreads();
  if (c < 64) {
    float o0 = 0.f, o1 = 0.f, o2 = 0.f;
    for (int j = 0; j < 128; ++j) {
      float w = Wc[c*128+j];
      o0 += w*up[j*3+0]; o1 += w*up[j*3+1]; o2 += w*up[j*3+2];
    }
    out[(size_t)b*192 + c*3 + 0] = o0;
    out[(size_t)b*192 + c*3 + 1] = o1;
    out[(size_t)b*192 + c*3 + 2] = o2;
  }
}

// ---------------------------------------------------------------------------
extern "C" void kernel_launch(void* const* d_in, const int* in_sizes, int n_in,
                              void* d_out, int out_size, void* d_ws, size_t ws_size,
                              hipStream_t stream) {
  const float* pc    = (const float*)d_in[0];
  const float* cWf   = (const float*)d_in[1];
  const float* cWd   = (const float*)d_in[2];
  const float* pposW = (const float*)d_in[3];
  const float* fcW   = (const float*)d_in[4];
  const float* ba0   = (const float*)d_in[5];
  const float* bf0   = (const float*)d_in[6];
  const float* ba1   = (const float*)d_in[7];
  const float* bf1   = (const float*)d_in[8];
  const float* bscW  = (const float*)d_in[9];
  const float* pWd   = (const float*)d_in[10];
  const float* aWd   = (const float*)d_in[11];
  const float* fccW  = (const float*)d_in[12];
  float* out = (float*)d_out;
  char* ws = (char*)d_ws;
  const size_t MB = 1u << 20;
  const size_t KB = 1u << 10;
  // workspace (channel-fast activations [b][col][c]):
  int*      idxb   = (int*)(ws);                 // 1.31 MB
  float*    X1     = (float*)(ws + 2*MB);        // 48 MB  [B][NCOLS][256]
  float*    X2     = (float*)(ws + 52*MB);       // 48 MB
  float*    conv   = (float*)(ws + 52*MB);       // 12 MB [B][NCOLS][64] (aliases X2)
  float*    T      = (float*)(ws + 102*MB);      // 48 MB [B][NCOLS][256]
  float*    T2     = T;                          // 24 MB (aliases T low half)
  float*    Hn     = (float*)(ws + 152*MB);      // 24 MB [B][NCOLS][128]
  float*    pooled = (float*)(ws + 178*MB);      // 6 KB [B][384]
  double*   pv     = (double*)(ws + 178*MB + 16*KB);   // 256 KB [B][64][128]
  int*      pn     = (int*)(ws + 178*MB + 288*KB);     // 128 KB
  float*    biasA  = (float*)(ws + 178*MB + 448*KB);   // 12 KB [B][3][256]
  float*    biasS  = (float*)(ws + 178*MB + 512*KB);   // 6 KB  [B][3][128]
  _Float16* Wsp    = (_Float16*)(ws + 179*MB);   // 3.5 MB (hi at [i], lo at [i+WTOT])
  _Float16* WspLo  = Wsp + WTOT;

  wsplit_kernel<<<WTOT/256, 256, 0, stream>>>(fcW, ba0, bf0, ba1, bf1, bscW, pWd, Wsp);
  knn_kernel<<<NB*NPTS/4, 512, 0, stream>>>(pc, idxb);
  edgeconv_kernel<<<NB*NPTS/2, 128, 0, stream>>>(pc, idxb, cWf, cWd, pposW, conv);
  gemm_mfma<<<dim3(192, 2, NB), 256, 0, stream>>>(Wsp + WOFF_FC, WspLo + WOFF_FC,
      conv, nullptr, nullptr, X1, 64, 64, 64, 256, 0, 0, 0);

  float* Xin = X1; float* Xout = X2;
  for (int i = 0; i < 5; ++i) {
    const _Float16* a0h = Wsp   + WOFF_A0 + (size_t)i*65536;
    const _Float16* a0l = WspLo + WOFF_A0 + (size_t)i*65536;
    const _Float16* f0h = Wsp   + WOFF_F0 + (size_t)i*32768;
    const _Float16* f0l = WspLo + WOFF_F0 + (size_t)i*32768;
    const _Float16* f1h = Wsp   + WOFF_F1 + (size_t)i*16384;
    const _Float16* f1l = WspLo + WOFF_F1 + (size_t)i*16384;
    const _Float16* a1h = Wsp   + WOFF_A1 + (size_t)i*16384;
    const _Float16* a1l = WspLo + WOFF_A1 + (size_t)i*16384;
    const _Float16* sch = Wsp   + WOFF_SC + (size_t)i*32768;
    const _Float16* scl = WspLo + WOFF_SC + (size_t)i*32768;
    const _Float16* pwh = Wsp   + WOFF_PW + (size_t)i*16384;
    const _Float16* pwl = WspLo + WOFF_PW + (size_t)i*16384;
    int KA = (i == 0) ? 256 : 128;              // concat channels via bias for i>0
    const float* bA = (i == 0) ? nullptr : biasA;
    const float* bS = (i == 0) ? nullptr : biasS;
    const float* lp = (i == 0) ? nullptr : pooled;
    if (i > 0) {
      bias2_kernel<<<(NB*3*384+255)/256,256,0,stream>>>(
          ba0 + (size_t)i*65536, bscW + (size_t)i*32768, pooled, biasA, biasS);
    }
    // FUSED: U = leaky(concat(X), a0 @ concat(X) (+biasA)) -> T
    gemm_leaky<2><<<dim3(NPTS/64, 2, NB), 256, 0, stream>>>(a0h, a0l, Xin, lp, bA, T,
        KA, 256, 256, 256, 256);
    // Hn = f0 @ U
    gemm_mfma<<<dim3(192,1,NB),256,0,stream>>>(f0h, f0l, T, nullptr, nullptr, Hn,
        256, 256, 256, 128, 0, 0, 0);
    // FUSED: U2 = leaky(Hn, a1 @ Hn) -> T2
    gemm_leaky<1><<<dim3(NPTS/32, 1, NB), 256, 0, stream>>>(a1h, a1l, Hn, nullptr, nullptr, T2,
        128, 128, 128, 128, 0);
    // DUAL: Xout = f1 @ U2 + sc @ concat(X) (+biasS)
    gemm_dual<<<dim3(192,1,NB),256,0,stream>>>(f1h, f1l, sch, scl, T2, Xin, bS, Xout,
        KA, 256, 128);
    // FUSED: Dm = pw @ net ; per-channel pool partials over 64-n chunks
    gemm_pool<<<dim3(NPTS/64,1,NB),256,0,stream>>>(pwh, pwl, Xout, pv, pn);
    pool2_kernel<<<NB,128,0,stream>>>(pv, pn, Xout, pooled, 256);
    if (i < 4) { float* tmp = Xin; Xin = Xout; Xout = tmp; }
  }
  head_kernel<<<NB,128,0,stream>>>(pooled, aWd, fccW, out);
}